// Round 5
// baseline (100.375 us; speedup 1.0000x reference)
//
#include <hip/hip_runtime.h>
#include <cmath>

// SSIM fused kernel v5: separable 11x11 gaussian, tile 32 cols x 54 rows.
// - hb stores rows in even/odd-interleaved PHYSICAL order: even logical rows
//   at phys 0..31, odd at phys 32..63. Phase-2's 2-rows-per-thread window then
//   reads unit-stride physical rows at every tap -> wave reads a contiguous
//   1024B window -> zero LDS bank conflicts (v4's stride-2 cost +4cyc/read).
// - LDS = 5*64*32*4 = 40960 B exactly; no other LDS -> 4 blocks/CU.
// - Phase 1: exactly 2 static iterations per thread (64 phys rows * 8 cg).
// - Per-wave partials (no cross-wave LDS reduce).

#define W 512
#define H 512
#define OWD 502
#define OHD 502
#define TILEC 32
#define TILER 54
#define INR 64            // phys rows: 32 even + 32 odd (logical 0..63)
#define NVALID 12096192   // 48 * 502 * 502
#define NBLKX 16
#define NBLKY 10
#define NPART (NBLKX * NBLKY * 48 * 4)   // one partial per wave

struct Weights { float g[11]; };

__global__ __launch_bounds__(256) void ssim_kernel(
    const float* __restrict__ x, const float* __restrict__ y,
    float* __restrict__ partial, float* __restrict__ accum, int use_atomic, Weights wt)
{
    __shared__ __align__(16) float hb[5][INR][TILEC];

    const int tid = threadIdx.x;
    const int r0 = blockIdx.y * TILER;
    const int c0 = blockIdx.x * TILEC;
    const size_t plane = (size_t)blockIdx.z * (W * H);
    const float* xp = x + plane;
    const float* yp = y + plane;

    // ---- Phase 1: horizontal pass over 64 physical rows x 8 col-groups.
    // phys p < 32 -> logical row 2p (even); p >= 32 -> logical 2(p-32)+1 (odd).
    #pragma unroll
    for (int k = 0; k < 2; k++) {
        const int i = tid + 256 * k;
        const int p = i >> 3;                 // physical row 0..63
        const int cg = (i & 7) << 2;          // col group offset 0..28
        const int lr = (p < 32) ? (2 * p) : (2 * (p - 32) + 1);  // logical row
        const int gr = r0 + lr;
        float xv[16], yv[16];
        if (gr < H) {
            const float* xr = xp + (size_t)gr * W;
            const float* yr = yp + (size_t)gr * W;
            #pragma unroll
            for (int q = 0; q < 4; q++) {
                const int gc = c0 + cg + 4 * q;
                float4 a = make_float4(0.f, 0.f, 0.f, 0.f);
                float4 b = make_float4(0.f, 0.f, 0.f, 0.f);
                if (gc < W) {  // W%4==0, gc%4==0 -> float4 fully in or out
                    a = *(const float4*)(xr + gc);
                    b = *(const float4*)(yr + gc);
                }
                xv[4*q+0] = a.x; xv[4*q+1] = a.y; xv[4*q+2] = a.z; xv[4*q+3] = a.w;
                yv[4*q+0] = b.x; yv[4*q+1] = b.y; yv[4*q+2] = b.z; yv[4*q+3] = b.w;
            }
        } else {
            #pragma unroll
            for (int j = 0; j < 16; j++) { xv[j] = 0.f; yv[j] = 0.f; }
        }
        // Hoisted products: compute xx/yy/xy once (not per tap).
        float xxv[16], yyv[16], xyv[16];
        #pragma unroll
        for (int j = 0; j < 16; j++) {
            xxv[j] = xv[j] * xv[j];
            yyv[j] = yv[j] * yv[j];
            xyv[j] = xv[j] * yv[j];
        }
        float m1[4]  = {0.f, 0.f, 0.f, 0.f};
        float m2[4]  = {0.f, 0.f, 0.f, 0.f};
        float e11[4] = {0.f, 0.f, 0.f, 0.f};
        float e22[4] = {0.f, 0.f, 0.f, 0.f};
        float e12[4] = {0.f, 0.f, 0.f, 0.f};
        #pragma unroll
        for (int k2 = 0; k2 < 11; k2++) {
            const float w = wt.g[k2];
            #pragma unroll
            for (int j = 0; j < 4; j++) {
                m1[j]  += w * xv[j + k2];
                m2[j]  += w * yv[j + k2];
                e11[j] += w * xxv[j + k2];
                e22[j] += w * yyv[j + k2];
                e12[j] += w * xyv[j + k2];
            }
        }
        *(float4*)&hb[0][p][cg] = make_float4(m1[0], m1[1], m1[2], m1[3]);
        *(float4*)&hb[1][p][cg] = make_float4(m2[0], m2[1], m2[2], m2[3]);
        *(float4*)&hb[2][p][cg] = make_float4(e11[0], e11[1], e11[2], e11[3]);
        *(float4*)&hb[3][p][cg] = make_float4(e22[0], e22[1], e22[2], e22[3]);
        *(float4*)&hb[4][p][cg] = make_float4(e12[0], e12[1], e12[2], e12[3]);
    }
    __syncthreads();

    // ---- Phase 2: vertical pass + SSIM. Threads with rp<27: 2 rows x 4 cols.
    float lsum = 0.f;
    {
        const int rp = tid >> 3;         // row pair 0..31 (27 used)
        const int cg = (tid & 7) << 2;   // col group
        if (rp < 27) {
            float a[5][2][4];
            #pragma unroll
            for (int j = 0; j < 5; j++)
                #pragma unroll
                for (int rr = 0; rr < 2; rr++)
                    #pragma unroll
                    for (int e = 0; e < 4; e++) a[j][rr][e] = 0.f;

            #pragma unroll
            for (int t = 0; t < 12; t++) {
                // logical row 2rp+t -> physical: even rows at p/2, odd at 32+p/2
                const int prow = ((t & 1) == 0) ? (rp + (t >> 1))
                                                : (32 + rp + (t >> 1));
                float4 v[5];
                #pragma unroll
                for (int j = 0; j < 5; j++) v[j] = *(const float4*)&hb[j][prow][cg];
                if (t <= 10) {   // tap for output row 0 (compile-time)
                    const float w = wt.g[t];
                    #pragma unroll
                    for (int j = 0; j < 5; j++) {
                        a[j][0][0] += w * v[j].x; a[j][0][1] += w * v[j].y;
                        a[j][0][2] += w * v[j].z; a[j][0][3] += w * v[j].w;
                    }
                }
                if (t >= 1) {    // tap for output row 1 (compile-time)
                    const float w = wt.g[t - 1];
                    #pragma unroll
                    for (int j = 0; j < 5; j++) {
                        a[j][1][0] += w * v[j].x; a[j][1][1] += w * v[j].y;
                        a[j][1][2] += w * v[j].z; a[j][1][3] += w * v[j].w;
                    }
                }
            }

            const float C1 = 1e-4f;   // (0.01*1)^2
            const float C2 = 9e-4f;   // (0.03*1)^2
            #pragma unroll
            for (int rr = 0; rr < 2; rr++) {
                const int orow = r0 + 2 * rp + rr;
                if (orow < OHD) {
                    #pragma unroll
                    for (int e = 0; e < 4; e++) {
                        const int ocol = c0 + cg + e;
                        if (ocol < OWD) {
                            const float mu1 = a[0][rr][e], mu2 = a[1][rr][e];
                            const float mu12 = mu1 * mu2;
                            const float mu1s = mu1 * mu1;
                            const float mu2s = mu2 * mu2;
                            const float s11 = a[2][rr][e] - mu1s;
                            const float s22 = a[3][rr][e] - mu2s;
                            const float s12 = a[4][rr][e] - mu12;
                            const float num = (2.f * mu12 + C1) * (2.f * s12 + C2);
                            const float den = (mu1s + mu2s + C1) * (s11 + s22 + C2);
                            lsum += num / den;
                        }
                    }
                }
            }
        }
    }

    // ---- Per-wave reduction; one partial (or atomic) per wave.
    #pragma unroll
    for (int off = 32; off > 0; off >>= 1) lsum += __shfl_down(lsum, off, 64);
    if ((tid & 63) == 0) {
        const int wave = tid >> 6;
        const int bid = (blockIdx.z * NBLKY + blockIdx.y) * NBLKX + blockIdx.x;
        if (use_atomic) unsafeAtomicAdd(accum, lsum);
        else partial[bid * 4 + wave] = lsum;
    }
}

__global__ __launch_bounds__(1024) void reduce_kernel(
    const float* __restrict__ partial, float* __restrict__ out)
{
    __shared__ float ws[16];
    float s = 0.f;
    for (int i = threadIdx.x; i < NPART; i += 1024) s += partial[i];
    #pragma unroll
    for (int off = 32; off > 0; off >>= 1) s += __shfl_down(s, off, 64);
    const int wave = threadIdx.x >> 6;
    if ((threadIdx.x & 63) == 0) ws[wave] = s;
    __syncthreads();
    if (threadIdx.x == 0) {
        float t = 0.f;
        #pragma unroll
        for (int i = 0; i < 16; i++) t += ws[i];
        out[0] = t * (1.0f / (float)NVALID);
    }
}

__global__ void finalize_kernel(const float* __restrict__ accum, float* __restrict__ out) {
    out[0] = accum[0] * (1.0f / (float)NVALID);
}

extern "C" void kernel_launch(void* const* d_in, const int* in_sizes, int n_in,
                              void* d_out, int out_size, void* d_ws, size_t ws_size,
                              hipStream_t stream) {
    const float* x = (const float*)d_in[0];
    const float* y = (const float*)d_in[1];
    float* out = (float*)d_out;
    float* ws = (float*)d_ws;

    // Gaussian window, computed in double like the numpy reference, cast to f32.
    Weights wt;
    {
        double g[11], s = 0.0;
        for (int i = 0; i < 11; i++) {
            double d = (double)(i - 5);
            g[i] = exp(-(d * d) / (2.0 * 1.5 * 1.5));
            s += g[i];
        }
        for (int i = 0; i < 11; i++) wt.g[i] = (float)(g[i] / s);
    }

    dim3 grid(NBLKX, NBLKY, 48);
    const int use_atomic = (ws_size < (size_t)NPART * sizeof(float)) ? 1 : 0;
    if (use_atomic) {
        hipMemsetAsync(ws, 0, sizeof(float), stream);
        ssim_kernel<<<grid, 256, 0, stream>>>(x, y, ws, ws, 1, wt);
        finalize_kernel<<<1, 1, 0, stream>>>(ws, out);
    } else {
        ssim_kernel<<<grid, 256, 0, stream>>>(x, y, ws, ws, 0, wt);
        reduce_kernel<<<1, 1024, 0, stream>>>(ws, out);
    }
}

// Round 6
// 88.741 us; speedup vs baseline: 1.1311x; 1.1311x over previous
//
#include <hip/hip_runtime.h>
#include <cmath>

// SSIM fused kernel v6: separable 11x11 gaussian, tile 32 cols x 64 rows.
// - 4 planes (not 5): SSIM only needs sigma1_sq+sigma2_sq as a sum, so
//   convolve (x^2+y^2) as one plane. -20% conv FMAs, LDS, phase-2 reads.
// - v4 geometry: 6144 blocks, all 256 threads active in phase 2 (2 rows x 4
//   cols each), vertical halo 74/64 = 1.16.
// - v5's even/odd interleaved physical row layout (evens phys 0..36, odds
//   37..73): each tap reads 8 consecutive phys rows per wave = contiguous
//   1024B window -> zero LDS bank conflicts (measured in v5).

#define W 512
#define H 512
#define OWD 502
#define OHD 502
#define TILEC 32
#define TILER 64
#define INR 74            // logical halo'd rows; phys: 37 even + 37 odd
#define ESPLIT 37         // phys offset of odd rows
#define NVALID 12096192   // 48 * 502 * 502
#define NBLKX 16
#define NBLKY 8
#define NPART (NBLKX * NBLKY * 48 * 4)   // one partial per wave

struct Weights { float g[11]; };

__global__ __launch_bounds__(256) void ssim_kernel(
    const float* __restrict__ x, const float* __restrict__ y,
    float* __restrict__ partial, float* __restrict__ accum, int use_atomic, Weights wt)
{
    __shared__ __align__(16) float hb[4][INR][TILEC];

    const int tid = threadIdx.x;
    const int r0 = blockIdx.y * TILER;
    const int c0 = blockIdx.x * TILEC;
    const size_t plane = (size_t)blockIdx.z * (W * H);
    const float* xp = x + plane;
    const float* yp = y + plane;

    // ---- Phase 1: horizontal pass over 74 physical rows x 8 col-groups.
    // phys p < 37 -> logical row 2p (even); p >= 37 -> logical 2(p-37)+1 (odd).
    for (int i = tid; i < INR * 8; i += 256) {
        const int p = i >> 3;                 // physical row 0..73
        const int cg = (i & 7) << 2;          // col group offset 0..28
        const int lr = (p < ESPLIT) ? (2 * p) : (2 * (p - ESPLIT) + 1);
        const int gr = r0 + lr;
        float xv[16], yv[16];
        if (gr < H) {
            const float* xr = xp + (size_t)gr * W;
            const float* yr = yp + (size_t)gr * W;
            #pragma unroll
            for (int q = 0; q < 4; q++) {
                const int gc = c0 + cg + 4 * q;
                float4 a = make_float4(0.f, 0.f, 0.f, 0.f);
                float4 b = make_float4(0.f, 0.f, 0.f, 0.f);
                if (gc < W) {  // W%4==0, gc%4==0 -> float4 fully in or out
                    a = *(const float4*)(xr + gc);
                    b = *(const float4*)(yr + gc);
                }
                xv[4*q+0] = a.x; xv[4*q+1] = a.y; xv[4*q+2] = a.z; xv[4*q+3] = a.w;
                yv[4*q+0] = b.x; yv[4*q+1] = b.y; yv[4*q+2] = b.z; yv[4*q+3] = b.w;
            }
        } else {
            #pragma unroll
            for (int j = 0; j < 16; j++) { xv[j] = 0.f; yv[j] = 0.f; }
        }
        // Hoisted products: ss = x^2 + y^2 (one plane), xy.
        float ssv[16], xyv[16];
        #pragma unroll
        for (int j = 0; j < 16; j++) {
            ssv[j] = xv[j] * xv[j] + yv[j] * yv[j];
            xyv[j] = xv[j] * yv[j];
        }
        float m1[4]  = {0.f, 0.f, 0.f, 0.f};
        float m2[4]  = {0.f, 0.f, 0.f, 0.f};
        float ms[4]  = {0.f, 0.f, 0.f, 0.f};
        float mx[4]  = {0.f, 0.f, 0.f, 0.f};
        #pragma unroll
        for (int k2 = 0; k2 < 11; k2++) {
            const float w = wt.g[k2];
            #pragma unroll
            for (int j = 0; j < 4; j++) {
                m1[j] += w * xv[j + k2];
                m2[j] += w * yv[j + k2];
                ms[j] += w * ssv[j + k2];
                mx[j] += w * xyv[j + k2];
            }
        }
        *(float4*)&hb[0][p][cg] = make_float4(m1[0], m1[1], m1[2], m1[3]);
        *(float4*)&hb[1][p][cg] = make_float4(m2[0], m2[1], m2[2], m2[3]);
        *(float4*)&hb[2][p][cg] = make_float4(ms[0], ms[1], ms[2], ms[3]);
        *(float4*)&hb[3][p][cg] = make_float4(mx[0], mx[1], mx[2], mx[3]);
    }
    __syncthreads();

    // ---- Phase 2: vertical pass + SSIM. All 256 threads: 2 rows x 4 cols.
    float lsum = 0.f;
    {
        const int rp = tid >> 3;         // row pair 0..31 -> rows 2rp, 2rp+1
        const int cg = (tid & 7) << 2;   // col group
        float a[4][2][4];
        #pragma unroll
        for (int j = 0; j < 4; j++)
            #pragma unroll
            for (int rr = 0; rr < 2; rr++)
                #pragma unroll
                for (int e = 0; e < 4; e++) a[j][rr][e] = 0.f;

        #pragma unroll
        for (int t = 0; t < 12; t++) {
            // logical row 2rp+t -> physical: even at rp + t/2, odd at ESPLIT + rp + (t-1)/2
            const int prow = ((t & 1) == 0) ? (rp + (t >> 1))
                                            : (ESPLIT + rp + (t >> 1));
            float4 v[4];
            #pragma unroll
            for (int j = 0; j < 4; j++) v[j] = *(const float4*)&hb[j][prow][cg];
            if (t <= 10) {   // tap for output row 0 (compile-time)
                const float w = wt.g[t];
                #pragma unroll
                for (int j = 0; j < 4; j++) {
                    a[j][0][0] += w * v[j].x; a[j][0][1] += w * v[j].y;
                    a[j][0][2] += w * v[j].z; a[j][0][3] += w * v[j].w;
                }
            }
            if (t >= 1) {    // tap for output row 1 (compile-time)
                const float w = wt.g[t - 1];
                #pragma unroll
                for (int j = 0; j < 4; j++) {
                    a[j][1][0] += w * v[j].x; a[j][1][1] += w * v[j].y;
                    a[j][1][2] += w * v[j].z; a[j][1][3] += w * v[j].w;
                }
            }
        }

        const float C1 = 1e-4f;   // (0.01*1)^2
        const float C2 = 9e-4f;   // (0.03*1)^2
        #pragma unroll
        for (int rr = 0; rr < 2; rr++) {
            const int orow = r0 + 2 * rp + rr;
            if (orow < OHD) {
                #pragma unroll
                for (int e = 0; e < 4; e++) {
                    const int ocol = c0 + cg + e;
                    if (ocol < OWD) {
                        const float mu1 = a[0][rr][e], mu2 = a[1][rr][e];
                        const float mu12 = mu1 * mu2;
                        const float mu1s = mu1 * mu1;
                        const float mu2s = mu2 * mu2;
                        const float sss = a[2][rr][e] - mu1s - mu2s;  // s11+s22
                        const float s12 = a[3][rr][e] - mu12;
                        const float num = (2.f * mu12 + C1) * (2.f * s12 + C2);
                        const float den = (mu1s + mu2s + C1) * (sss + C2);
                        lsum += num / den;
                    }
                }
            }
        }
    }

    // ---- Per-wave reduction; one partial (or atomic) per wave.
    #pragma unroll
    for (int off = 32; off > 0; off >>= 1) lsum += __shfl_down(lsum, off, 64);
    if ((tid & 63) == 0) {
        const int wave = tid >> 6;
        const int bid = (blockIdx.z * NBLKY + blockIdx.y) * NBLKX + blockIdx.x;
        if (use_atomic) unsafeAtomicAdd(accum, lsum);
        else partial[bid * 4 + wave] = lsum;
    }
}

__global__ __launch_bounds__(1024) void reduce_kernel(
    const float* __restrict__ partial, float* __restrict__ out)
{
    __shared__ float ws[16];
    float s = 0.f;
    for (int i = threadIdx.x; i < NPART; i += 1024) s += partial[i];
    #pragma unroll
    for (int off = 32; off > 0; off >>= 1) s += __shfl_down(s, off, 64);
    const int wave = threadIdx.x >> 6;
    if ((threadIdx.x & 63) == 0) ws[wave] = s;
    __syncthreads();
    if (threadIdx.x == 0) {
        float t = 0.f;
        #pragma unroll
        for (int i = 0; i < 16; i++) t += ws[i];
        out[0] = t * (1.0f / (float)NVALID);
    }
}

__global__ void finalize_kernel(const float* __restrict__ accum, float* __restrict__ out) {
    out[0] = accum[0] * (1.0f / (float)NVALID);
}

extern "C" void kernel_launch(void* const* d_in, const int* in_sizes, int n_in,
                              void* d_out, int out_size, void* d_ws, size_t ws_size,
                              hipStream_t stream) {
    const float* x = (const float*)d_in[0];
    const float* y = (const float*)d_in[1];
    float* out = (float*)d_out;
    float* ws = (float*)d_ws;

    // Gaussian window, computed in double like the numpy reference, cast to f32.
    Weights wt;
    {
        double g[11], s = 0.0;
        for (int i = 0; i < 11; i++) {
            double d = (double)(i - 5);
            g[i] = exp(-(d * d) / (2.0 * 1.5 * 1.5));
            s += g[i];
        }
        for (int i = 0; i < 11; i++) wt.g[i] = (float)(g[i] / s);
    }

    dim3 grid(NBLKX, NBLKY, 48);
    const int use_atomic = (ws_size < (size_t)NPART * sizeof(float)) ? 1 : 0;
    if (use_atomic) {
        hipMemsetAsync(ws, 0, sizeof(float), stream);
        ssim_kernel<<<grid, 256, 0, stream>>>(x, y, ws, ws, 1, wt);
        finalize_kernel<<<1, 1, 0, stream>>>(ws, out);
    } else {
        ssim_kernel<<<grid, 256, 0, stream>>>(x, y, ws, ws, 0, wt);
        reduce_kernel<<<1, 1024, 0, stream>>>(ws, out);
    }
}